// Round 1
// baseline (17207.422 us; speedup 1.0000x reference)
//
#include <hip/hip_runtime.h>

typedef _Float16 f16x8 __attribute__((ext_vector_type(8)));
typedef _Float16 f16x2 __attribute__((ext_vector_type(2)));

union F16x8U { f16x8 v8; f16x2 v2[4]; };

__device__ __forceinline__ float dot2acc(f16x2 a, f16x2 b, float c) {
#if __has_builtin(__builtin_amdgcn_fdot2)
    return __builtin_amdgcn_fdot2(a, b, c, false);
#else
    return c + (float)a[0] * (float)b[0] + (float)a[1] * (float)b[1];
#endif
}

__device__ __forceinline__ float sigmoidf_(float x) {
    return __builtin_amdgcn_rcpf(1.f + __expf(-x));
}

__device__ __forceinline__ float tanhf_(float x) {
    float a = fabsf(x);
    float e = __expf(-2.f * a);
    float r = (1.f - e) * __builtin_amdgcn_rcpf(1.f + e);
    return copysignf(r, x);
}

// ---------------------------------------------------------------------------
// Pack Whh1/Wih1/Wih2 into fp16, k-major 16B chunks for coalesced streaming.
// whhp layout: chunk[(k8*3+g)*384 + j] = 8 fp16 = Whh1[g*384+j][k8*8 .. +7]
// wihp layout: same with K padded 20->24 (zeros)
// wih2h: plain row-major fp16 copy of Wih2 (48x384)
// ---------------------------------------------------------------------------
__global__ void pack_weights(const float* __restrict__ Whh1,
                             const float* __restrict__ Wih1,
                             const float* __restrict__ Wih2,
                             _Float16* __restrict__ wsbase) {
    int tid = blockIdx.x * 256 + threadIdx.x;
    _Float16* whhp  = wsbase;
    _Float16* wihp  = wsbase + 442368;
    _Float16* wih2h = wsbase + 470016;
    if (tid < 55296) {
        int j = tid % 384, g = (tid / 384) % 3, k8 = tid / 1152;
        int row = g * 384 + j;
        f16x8 v;
#pragma unroll
        for (int c = 0; c < 8; ++c) v[c] = (_Float16)Whh1[row * 384 + k8 * 8 + c];
        *(f16x8*)(whhp + tid * 8) = v;
    } else if (tid < 58752) {
        int t2 = tid - 55296;
        int j = t2 % 384, g = (t2 / 384) % 3, k8 = t2 / 1152;
        int row = g * 384 + j;
        f16x8 v;
#pragma unroll
        for (int c = 0; c < 8; ++c) {
            int kk = k8 * 8 + c;
            v[c] = (kk < 20) ? (_Float16)Wih1[row * 20 + kk] : (_Float16)0.f;
        }
        *(f16x8*)(wihp + t2 * 8) = v;
    } else if (tid < 77184) {
        int t3 = tid - 58752;
        wih2h[t3] = (_Float16)Wih2[t3];
    }
}

// ---------------------------------------------------------------------------
// Fused forward scan: GRU1(20->384) -> GRU2(384->16) -> ReLU -> FC -> 2*tanh
// One block per batch element; 384 threads; thread j owns gate element j
// (rows j, j+384, j+768 of the 1152 gate rows -> r_j, z_j, n_j locally).
// ---------------------------------------------------------------------------
__global__ __launch_bounds__(384) void gru_fwd(
    const float* __restrict__ x, const float* __restrict__ h1_0,
    const float* __restrict__ h2_0,
    const float* __restrict__ bih1, const float* __restrict__ bhh1,
    const _Float16* __restrict__ whhp, const _Float16* __restrict__ wihp,
    const _Float16* __restrict__ wih2h,
    const float* __restrict__ Whh2, const float* __restrict__ bih2,
    const float* __restrict__ bhh2,
    const float* __restrict__ Wfc, const float* __restrict__ bfc,
    float* __restrict__ out_xmid, float* __restrict__ h1f_o,
    float* __restrict__ h2f_o) {
    const int b = blockIdx.x;
    const int j = threadIdx.x;

    __shared__ __align__(16) _Float16 h1h[384];
    __shared__ __align__(16) _Float16 xsh[24];
    __shared__ float h1f[384];
    __shared__ float part[384];
    __shared__ float sxp2[48], sgh2[48];
    __shared__ float h2f[16], y2s[16];

    float h0 = h1_0[b * 384 + j];
    h1f[j] = h0;
    h1h[j] = (_Float16)h0;
    if (j < 16) h2f[j] = h2_0[b * 16 + j];
    if (j < 24) xsh[j] = (_Float16)0.f;

    const float cbr  = bih1[j] + bhh1[j];
    const float cbz  = bih1[384 + j] + bhh1[384 + j];
    const float cbnx = bih1[768 + j];
    const float cbnh = bhh1[768 + j];

    const f16x8* Wh = (const f16x8*)whhp;
    const f16x8* Wi = (const f16x8*)wihp;
    const float* xb = x + (size_t)b * 2048 * 20;
    float* omid = out_xmid + (size_t)b * 2048 * 20;

    const int o   = j >> 3;  // xp2 partial: output index
    const int seg = j & 7;   // xp2 partial: k segment

    __syncthreads();

    for (int t = 0; t < 2048; ++t) {
        if (j < 20) xsh[j] = (_Float16)xb[t * 20 + j];
        __syncthreads();  // S1: xsh ready, h1h stable

        float ar = cbr, az = cbz, axn = cbnx, ahn = cbnh;
        // x-projection part (K padded to 24)
#pragma unroll
        for (int k8 = 0; k8 < 3; ++k8) {
            F16x8U xv; xv.v8 = *(const f16x8*)(xsh + k8 * 8);
            F16x8U wr, wz, wn;
            wr.v8 = Wi[(k8 * 3 + 0) * 384 + j];
            wz.v8 = Wi[(k8 * 3 + 1) * 384 + j];
            wn.v8 = Wi[(k8 * 3 + 2) * 384 + j];
#pragma unroll
            for (int i = 0; i < 4; ++i) {
                ar  = dot2acc(wr.v2[i], xv.v2[i], ar);
                az  = dot2acc(wz.v2[i], xv.v2[i], az);
                axn = dot2acc(wn.v2[i], xv.v2[i], axn);
            }
        }
        // recurrent part, K=384
#pragma unroll 4
        for (int k8 = 0; k8 < 48; ++k8) {
            F16x8U hv; hv.v8 = *(const f16x8*)(h1h + k8 * 8);
            F16x8U wr, wz, wn;
            wr.v8 = Wh[(k8 * 3 + 0) * 384 + j];
            wz.v8 = Wh[(k8 * 3 + 1) * 384 + j];
            wn.v8 = Wh[(k8 * 3 + 2) * 384 + j];
#pragma unroll
            for (int i = 0; i < 4; ++i) {
                ar  = dot2acc(wr.v2[i], hv.v2[i], ar);
                az  = dot2acc(wz.v2[i], hv.v2[i], az);
                ahn = dot2acc(wn.v2[i], hv.v2[i], ahn);
            }
        }
        float r  = sigmoidf_(ar);
        float zz = sigmoidf_(az);
        float n  = tanhf_(axn + r * ahn);
        float hn = (1.f - zz) * n + zz * h1f[j];
        __syncthreads();  // S2: all h1h reads done
        h1f[j] = hn;
        h1h[j] = (_Float16)hn;
        __syncthreads();  // S3: h1 updated

        // xp2 partials: 8 threads per output o, 48 k each (fp16 dot2)
        {
            const _Float16* hrow = h1h + seg * 48;
            const _Float16* wrow = wih2h + o * 384 + seg * 48;
            float acc = 0.f;
#pragma unroll
            for (int m = 0; m < 6; ++m) {
                F16x8U hv; hv.v8 = *(const f16x8*)(hrow + m * 8);
                F16x8U wv; wv.v8 = *(const f16x8*)(wrow + m * 8);
#pragma unroll
                for (int i = 0; i < 4; ++i)
                    acc = dot2acc(wv.v2[i], hv.v2[i], acc);
            }
            part[j] = acc;
        }
        __syncthreads();  // S4

        if (j < 48) {
            float s = bih2[j];
#pragma unroll
            for (int sg = 0; sg < 8; ++sg) s += part[j * 8 + sg];
            float g = bhh2[j];
#pragma unroll
            for (int k = 0; k < 16; ++k) g += h2f[k] * Whh2[j * 16 + k];
            sxp2[j] = s;
            sgh2[j] = g;
        }
        __syncthreads();  // S5

        if (j < 16) {
            float r2  = sigmoidf_(sxp2[j] + sgh2[j]);
            float z2  = sigmoidf_(sxp2[16 + j] + sgh2[16 + j]);
            float n2  = tanhf_(sxp2[32 + j] + r2 * sgh2[32 + j]);
            float h2n = (1.f - z2) * n2 + z2 * h2f[j];
            h2f[j] = h2n;
            y2s[j] = fmaxf(h2n, 0.f);
        }
        __syncthreads();  // S6

        if (j < 20) {
            float a = bfc[j];
#pragma unroll
            for (int k = 0; k < 16; ++k) a += y2s[k] * Wfc[j * 16 + k];
            omid[t * 20 + j] = 2.f * tanhf_(a);
        }
        // next S1 orders xsh rewrite vs. this iteration's reads
    }
    __syncthreads();
    h1f_o[b * 384 + j] = h1f[j];
    if (j < 16) h2f_o[b * 16 + j] = h2f[j];
}

// ---------------------------------------------------------------------------
// GRU3 on flip(x_mid): one block (one wave) per batch; x_out = tanh(y3).
// ---------------------------------------------------------------------------
__global__ __launch_bounds__(64) void gru3_bwd(
    const float* __restrict__ xmid, const float* __restrict__ h3_0,
    const float* __restrict__ Wih3, const float* __restrict__ Whh3,
    const float* __restrict__ bih3, const float* __restrict__ bhh3,
    float* __restrict__ xout, float* __restrict__ h3f_o) {
    const int b = blockIdx.x;
    const int tid = threadIdx.x;
    __shared__ __align__(16) float h3s[20];
    __shared__ __align__(16) float xs[20];
    __shared__ float ssum[40], sxn[20], shn[20];

    float wi[20], wh[20];
    float bx = 0.f, bh = 0.f;
    if (tid < 60) {
#pragma unroll
        for (int k = 0; k < 20; ++k) {
            wi[k] = Wih3[tid * 20 + k];
            wh[k] = Whh3[tid * 20 + k];
        }
        bx = bih3[tid];
        bh = bhh3[tid];
    }
    if (tid < 20) h3s[tid] = h3_0[b * 20 + tid];
    const float* xm = xmid + (size_t)b * 2048 * 20;
    float* xo = xout + (size_t)b * 2048 * 20;
    __syncthreads();

    for (int t = 0; t < 2048; ++t) {
        int tr = 2047 - t;
        if (tid < 20) xs[tid] = xm[tr * 20 + tid];
        __syncthreads();
        if (tid < 60) {
            float ax = bx, ah = bh;
#pragma unroll
            for (int k = 0; k < 20; ++k) {
                ax += xs[k] * wi[k];
                ah += h3s[k] * wh[k];
            }
            if (tid < 40) ssum[tid] = ax + ah;
            else { sxn[tid - 40] = ax; shn[tid - 40] = ah; }
        }
        __syncthreads();
        if (tid < 20) {
            float r  = sigmoidf_(ssum[tid]);
            float z  = sigmoidf_(ssum[20 + tid]);
            float n  = tanhf_(sxn[tid] + r * shn[tid]);
            float hn = (1.f - z) * n + z * h3s[tid];
            h3s[tid] = hn;
            xo[t * 20 + tid] = tanhf_(hn);
        }
        __syncthreads();
    }
    if (tid < 20) h3f_o[b * 20 + tid] = h3s[tid];
}

extern "C" void kernel_launch(void* const* d_in, const int* in_sizes, int n_in,
                              void* d_out, int out_size, void* d_ws, size_t ws_size,
                              hipStream_t stream) {
    const float* x    = (const float*)d_in[0];
    const float* h1   = (const float*)d_in[1];
    const float* h2   = (const float*)d_in[2];
    const float* h3   = (const float*)d_in[3];
    const float* Wih1 = (const float*)d_in[4];
    const float* Whh1 = (const float*)d_in[5];
    const float* bih1 = (const float*)d_in[6];
    const float* bhh1 = (const float*)d_in[7];
    const float* Wih2 = (const float*)d_in[8];
    const float* Whh2 = (const float*)d_in[9];
    const float* bih2 = (const float*)d_in[10];
    const float* bhh2 = (const float*)d_in[11];
    const float* Wih3 = (const float*)d_in[12];
    const float* Whh3 = (const float*)d_in[13];
    const float* bih3 = (const float*)d_in[14];
    const float* bhh3 = (const float*)d_in[15];
    const float* Wfc  = (const float*)d_in[16];
    const float* bfc  = (const float*)d_in[17];

    float* out  = (float*)d_out;
    float* xmid = out;                  // (64,2048,20)
    float* xout = out + 2621440;        // (64,2048,20)
    float* h1f  = out + 5242880;        // (64,384)
    float* h2f  = out + 5267456;        // (64,16)
    float* h3f  = out + 5268480;        // (64,20)

    _Float16* wsh = (_Float16*)d_ws;

    pack_weights<<<302, 256, 0, stream>>>(Whh1, Wih1, Wih2, wsh);
    gru_fwd<<<64, 384, 0, stream>>>(x, h1, h2, bih1, bhh1,
                                    wsh, wsh + 442368, wsh + 470016,
                                    Whh2, bih2, bhh2, Wfc, bfc,
                                    xmid, h1f, h2f);
    gru3_bwd<<<64, 64, 0, stream>>>(xmid, h3, Wih3, Whh3, bih3, bhh3,
                                    xout, h3f);
}

// Round 2
// 17081.203 us; speedup vs baseline: 1.0074x; 1.0074x over previous
//
#include <hip/hip_runtime.h>

typedef _Float16 f16x8 __attribute__((ext_vector_type(8)));
typedef _Float16 f16x2 __attribute__((ext_vector_type(2)));

union F16x8U { f16x8 v8; f16x2 v2[4]; };

__device__ __forceinline__ float dot2acc(f16x2 a, f16x2 b, float c) {
#if __has_builtin(__builtin_amdgcn_fdot2)
    return __builtin_amdgcn_fdot2(a, b, c, false);
#else
    return c + (float)a[0] * (float)b[0] + (float)a[1] * (float)b[1];
#endif
}

__device__ __forceinline__ float sigmoidf_(float x) {
    return __builtin_amdgcn_rcpf(1.f + __expf(-x));
}

__device__ __forceinline__ float tanhf_(float x) {
    float a = fabsf(x);
    float e = __expf(-2.f * a);
    float r = (1.f - e) * __builtin_amdgcn_rcpf(1.f + e);
    return copysignf(r, x);
}

// ---------------------------------------------------------------------------
// Pack Whh1/Wih1/Wih2 into fp16.
// whhp: chunk[(k8*3+g)*384 + j] = Whh1[g*384+j][k8*8..+7]   (48 k8)
// wihp: same with K padded 20->24 (3 k8)
// wih2h: row-major fp16 (48 x 384)
// ---------------------------------------------------------------------------
__global__ void pack_weights(const float* __restrict__ Whh1,
                             const float* __restrict__ Wih1,
                             const float* __restrict__ Wih2,
                             _Float16* __restrict__ wsbase) {
    int tid = blockIdx.x * 256 + threadIdx.x;
    _Float16* whhp  = wsbase;
    _Float16* wihp  = wsbase + 442368;
    _Float16* wih2h = wsbase + 470016;
    if (tid < 55296) {
        int j = tid % 384, g = (tid / 384) % 3, k8 = tid / 1152;
        int row = g * 384 + j;
        f16x8 v;
#pragma unroll
        for (int c = 0; c < 8; ++c) v[c] = (_Float16)Whh1[row * 384 + k8 * 8 + c];
        *(f16x8*)(whhp + tid * 8) = v;
    } else if (tid < 58752) {
        int t2 = tid - 55296;
        int j = t2 % 384, g = (t2 / 384) % 3, k8 = t2 / 1152;
        int row = g * 384 + j;
        f16x8 v;
#pragma unroll
        for (int c = 0; c < 8; ++c) {
            int kk = k8 * 8 + c;
            v[c] = (kk < 20) ? (_Float16)Wih1[row * 20 + kk] : (_Float16)0.f;
        }
        *(f16x8*)(wihp + t2 * 8) = v;
    } else if (tid < 77184) {
        int t3 = tid - 58752;
        wih2h[t3] = (_Float16)Wih2[t3];
    }
}

// ---------------------------------------------------------------------------
// GRU1 scan. One block per batch, 768 threads = (j in [0,384)) x (K-half).
// half0: Whh k8 0..23 + x-projection; half1: Whh k8 24..47.
// Writes xp2 partial sums (48 per (b,t)) to ws for the tail kernel.
// 3 barriers per step.
// ---------------------------------------------------------------------------
__global__ __launch_bounds__(768) void gru1_scan(
    const float* __restrict__ x, const float* __restrict__ h1_0,
    const float* __restrict__ bih1, const float* __restrict__ bhh1,
    const _Float16* __restrict__ whhp, const _Float16* __restrict__ wihp,
    const _Float16* __restrict__ wih2h,
    float* __restrict__ sxp2g, float* __restrict__ h1f_o) {
    const int b = blockIdx.x;
    const int tid = threadIdx.x;
    const int half = tid >= 384;
    const int j = half ? tid - 384 : tid;

    __shared__ __align__(16) _Float16 h1h[384];
    __shared__ __align__(16) _Float16 xsh[2][24];
    __shared__ __align__(16) float part[384 * 8];
    __shared__ __align__(16) float part2[768];

    float hprev = 0.f;
    if (tid < 384) {
        hprev = h1_0[b * 384 + tid];
        h1h[tid] = (_Float16)hprev;
    }
    float cbr = 0.f, cbz = 0.f, chn = 0.f, cxn = 0.f;
    if (!half) {
        cbr = bih1[j] + bhh1[j];
        cbz = bih1[384 + j] + bhh1[384 + j];
        cxn = bih1[768 + j];
        chn = bhh1[768 + j];
    }
    const float* xb = x + (size_t)b * 40960;
    if (tid < 24) {
        xsh[0][tid] = (_Float16)((tid < 20) ? xb[tid] : 0.f);
        xsh[1][tid] = (_Float16)0.f;
    }
    __syncthreads();

    const f16x8* Wh = (const f16x8*)whhp;
    const f16x8* Wi = (const f16x8*)wihp;
    const f16x8* hc = (const f16x8*)h1h;
    const int o = tid >> 4, seg = tid & 15;
    const f16x8* w2base = (const f16x8*)(wih2h + o * 384 + seg * 24);
    const int k0 = half ? 24 : 0;

    for (int t = 0; t < 2048; ++t) {
        // stage next x (double-buffered)
        if (tid < 20 && t + 1 < 2048)
            xsh[(t + 1) & 1][tid] = (_Float16)xb[(t + 1) * 20 + tid];

        // P1: half-K partial dots
        float ar = cbr, az = cbz, ahn = chn, axn = cxn;
#pragma unroll 8
        for (int kk = 0; kk < 24; ++kk) {
            const int k8 = k0 + kk;
            F16x8U hv; hv.v8 = hc[k8];
            F16x8U wr, wz, wn;
            wr.v8 = Wh[(k8 * 3 + 0) * 384 + j];
            wz.v8 = Wh[(k8 * 3 + 1) * 384 + j];
            wn.v8 = Wh[(k8 * 3 + 2) * 384 + j];
#pragma unroll
            for (int i = 0; i < 4; ++i) {
                ar  = dot2acc(wr.v2[i], hv.v2[i], ar);
                az  = dot2acc(wz.v2[i], hv.v2[i], az);
                ahn = dot2acc(wn.v2[i], hv.v2[i], ahn);
            }
        }
        if (!half) {
            const _Float16* xs = xsh[t & 1];
#pragma unroll
            for (int k8 = 0; k8 < 3; ++k8) {
                F16x8U xv; xv.v8 = *(const f16x8*)(xs + k8 * 8);
                F16x8U wr, wz, wn;
                wr.v8 = Wi[(k8 * 3 + 0) * 384 + j];
                wz.v8 = Wi[(k8 * 3 + 1) * 384 + j];
                wn.v8 = Wi[(k8 * 3 + 2) * 384 + j];
#pragma unroll
                for (int i = 0; i < 4; ++i) {
                    ar  = dot2acc(wr.v2[i], xv.v2[i], ar);
                    az  = dot2acc(wz.v2[i], xv.v2[i], az);
                    axn = dot2acc(wn.v2[i], xv.v2[i], axn);
                }
            }
        }
        {
            float4 pv; pv.x = ar; pv.y = az; pv.z = ahn; pv.w = axn;
            *(float4*)&part[j * 8 + half * 4] = pv;
        }
        __syncthreads();  // S_b: partials ready

        if (tid < 384) {
            float4 a0 = *(const float4*)&part[tid * 8];
            float4 a1 = *(const float4*)&part[tid * 8 + 4];
            float r = sigmoidf_(a0.x + a1.x);
            float z = sigmoidf_(a0.y + a1.y);
            float n = tanhf_((a0.w + a1.w) + r * (a0.z + a1.z));
            hprev = (1.f - z) * n + z * hprev;
            h1h[tid] = (_Float16)hprev;
        }
        __syncthreads();  // S_c: new h ready

        // P3: xp2 partials — 16 threads per output o, K=24 each
        {
            const _Float16* hseg = (const _Float16*)h1h + seg * 24;
            float acc = 0.f;
#pragma unroll
            for (int m = 0; m < 3; ++m) {
                F16x8U hv; hv.v8 = *(const f16x8*)(hseg + m * 8);
                F16x8U wv; wv.v8 = w2base[m];
#pragma unroll
                for (int i = 0; i < 4; ++i)
                    acc = dot2acc(wv.v2[i], hv.v2[i], acc);
            }
            part2[o * 16 + seg] = acc;
        }
        __syncthreads();  // S_d: xp2 partials ready

        if (tid < 48) {
            float4 s0 = *(const float4*)&part2[tid * 16];
            float4 s1 = *(const float4*)&part2[tid * 16 + 4];
            float4 s2 = *(const float4*)&part2[tid * 16 + 8];
            float4 s3 = *(const float4*)&part2[tid * 16 + 12];
            float s = (s0.x + s0.y + s0.z + s0.w) + (s1.x + s1.y + s1.z + s1.w)
                    + (s2.x + s2.y + s2.z + s2.w) + (s3.x + s3.y + s3.z + s3.w);
            sxp2g[((size_t)b * 2048 + t) * 48 + tid] = s;
        }
        // next S_b orders P4/xsh-stage vs next step's rewrites
    }
    if (tid < 384) h1f_o[b * 384 + tid] = hprev;
}

// ---------------------------------------------------------------------------
// Tail: GRU2+ReLU+FC forward (from sxp2), then GRU3 reverse. One wave per
// batch, all cross-lane via shuffles — zero barriers in the step loops.
// ---------------------------------------------------------------------------
__global__ __launch_bounds__(64) void tail_scan(
    const float* __restrict__ sxp2g, const float* __restrict__ h2_0,
    const float* __restrict__ h3_0,
    const float* __restrict__ Whh2, const float* __restrict__ bih2,
    const float* __restrict__ bhh2,
    const float* __restrict__ Wfc, const float* __restrict__ bfc,
    const float* __restrict__ Wih3, const float* __restrict__ Whh3,
    const float* __restrict__ bih3, const float* __restrict__ bhh3,
    float* __restrict__ xmid, float* __restrict__ xout,
    float* __restrict__ h2f_o, float* __restrict__ h3f_o) {
    const int b = blockIdx.x;
    const int l = threadIdx.x;

    // ---- loop 1: GRU2 + ReLU + FC + 2*tanh ----
    float w2r[16]; float bx2 = 0.f, bh2 = 0.f;
    if (l < 48) {
#pragma unroll
        for (int k = 0; k < 16; ++k) w2r[k] = Whh2[l * 16 + k];
        bx2 = bih2[l]; bh2 = bhh2[l];
    }
    float wfc[16]; float bf = 0.f;
    if (l < 20) {
#pragma unroll
        for (int k = 0; k < 16; ++k) wfc[k] = Wfc[l * 16 + k];
        bf = bfc[l];
    }
    float h2 = (l < 16) ? h2_0[b * 16 + l] : 0.f;
    const float* sx = sxp2g + (size_t)b * 2048 * 48;
    float* xm = xmid + (size_t)b * 40960;
    float sxc = (l < 48) ? sx[l] : 0.f;

    for (int t = 0; t < 2048; ++t) {
        float sxnx = (l < 48 && t + 1 < 2048) ? sx[(t + 1) * 48 + l] : 0.f;
        float ax = sxc + bx2;
        float ah = bh2;
#pragma unroll
        for (int k = 0; k < 16; ++k) ah += __shfl(h2, k) * w2r[k];
        float s_  = ax + ah;
        float zpre = __shfl(s_, (16 + l) & 63);
        float xn3  = __shfl(ax, (32 + l) & 63);
        float ghn  = __shfl(ah, (32 + l) & 63);
        float r2 = sigmoidf_(s_);
        float z2 = sigmoidf_(zpre);
        float n2 = tanhf_(xn3 + r2 * ghn);
        float h2n = (1.f - z2) * n2 + z2 * h2;
        if (l < 16) h2 = h2n;
        float y2 = fmaxf(h2n, 0.f);
        float a = bf;
#pragma unroll
        for (int k = 0; k < 16; ++k) a += __shfl(y2, k) * wfc[k];
        if (l < 20) xm[t * 20 + l] = 2.f * tanhf_(a);
        sxc = sxnx;
    }
    if (l < 16) h2f_o[b * 16 + l] = h2;

    // ---- loop 2: GRU3 on reversed xmid ----
    float wi3[20], wh3[20]; float bx3 = 0.f, bh3 = 0.f;
    if (l < 60) {
#pragma unroll
        for (int k = 0; k < 20; ++k) {
            wi3[k] = Wih3[l * 20 + k];
            wh3[k] = Whh3[l * 20 + k];
        }
        bx3 = bih3[l]; bh3 = bhh3[l];
    }
    float h3 = (l < 20) ? h3_0[b * 20 + l] : 0.f;
    float* xo = xout + (size_t)b * 40960;
    float xv = (l < 20) ? xm[2047 * 20 + l] : 0.f;

    for (int t = 2047; t >= 0; --t) {
        float xnx = (l < 20 && t > 0) ? xm[(t - 1) * 20 + l] : 0.f;
        float ax = bx3, ah = bh3;
#pragma unroll
        for (int k = 0; k < 20; ++k) {
            ax += __shfl(xv, k) * wi3[k];
            ah += __shfl(h3, k) * wh3[k];
        }
        float s_  = ax + ah;
        float zpre = __shfl(s_, (20 + l) & 63);
        float xn_  = __shfl(ax, (40 + l) & 63);
        float ghn  = __shfl(ah, (40 + l) & 63);
        float r = sigmoidf_(s_);
        float z = sigmoidf_(zpre);
        float n = tanhf_(xn_ + r * ghn);
        float hn = (1.f - z) * n + z * h3;
        if (l < 20) {
            h3 = hn;
            xo[(2047 - t) * 20 + l] = tanhf_(hn);
        }
        xv = xnx;
    }
    if (l < 20) h3f_o[b * 20 + l] = h3;
}

extern "C" void kernel_launch(void* const* d_in, const int* in_sizes, int n_in,
                              void* d_out, int out_size, void* d_ws, size_t ws_size,
                              hipStream_t stream) {
    const float* x    = (const float*)d_in[0];
    const float* h1   = (const float*)d_in[1];
    const float* h2   = (const float*)d_in[2];
    const float* h3   = (const float*)d_in[3];
    const float* Wih1 = (const float*)d_in[4];
    const float* Whh1 = (const float*)d_in[5];
    const float* bih1 = (const float*)d_in[6];
    const float* bhh1 = (const float*)d_in[7];
    const float* Wih2 = (const float*)d_in[8];
    const float* Whh2 = (const float*)d_in[9];
    const float* bih2 = (const float*)d_in[10];
    const float* bhh2 = (const float*)d_in[11];
    const float* Wih3 = (const float*)d_in[12];
    const float* Whh3 = (const float*)d_in[13];
    const float* bih3 = (const float*)d_in[14];
    const float* bhh3 = (const float*)d_in[15];
    const float* Wfc  = (const float*)d_in[16];
    const float* bfc  = (const float*)d_in[17];

    float* out  = (float*)d_out;
    float* xmid = out;                  // (64,2048,20)
    float* xout = out + 2621440;        // (64,2048,20)
    float* h1f  = out + 5242880;        // (64,384)
    float* h2f  = out + 5267456;        // (64,16)
    float* h3f  = out + 5268480;        // (64,20)

    _Float16* wsh = (_Float16*)d_ws;
    float* sxp2 = (float*)((char*)d_ws + (1u << 20));  // 25.2 MB

    pack_weights<<<302, 256, 0, stream>>>(Whh1, Wih1, Wih2, wsh);
    gru1_scan<<<64, 768, 0, stream>>>(x, h1, bih1, bhh1,
                                      wsh, wsh + 442368, wsh + 470016,
                                      sxp2, h1f);
    tail_scan<<<64, 64, 0, stream>>>(sxp2, h2, h3,
                                     Whh2, bih2, bhh2, Wfc, bfc,
                                     Wih3, Whh3, bih3, bhh3,
                                     xmid, xout, h2f, h3f);
}